// Round 2
// baseline (1148.700 us; speedup 1.0000x reference)
//
#include <hip/hip_runtime.h>

#define NUM_K 1024
#define DIM 64
#define HWSZ 4096            // 64*64
#define NPIX 131072          // 32*64*64

// output element offsets (float32 elements)
#define OUT_Q    0u
#define OUT_LOSS 8388608u
#define OUT_IDX  8388609u
#define OUT_CS   8519681u
#define OUT_EMAW 8520705u
#define OUT_EMB  8586241u

// workspace layout (float32 elements)
#define WS_SE    0
#define WS_CNT   1024
#define WS_ESUM  2048
#define WS_LOSS  (2048 + 65536)
#define WS_ZERO_LEN (1024 + 65536 + 1)   // counts + esum + loss

// numpy pairwise_sum emulation for sum(a[i]^2), n=64 contiguous fp32:
// r[0..7]=sq[0..7]; r[j]+=sq[8i+j]; res=((r0+r1)+(r2+r3))+((r4+r5)+(r6+r7))
// contract(off) so fl(a*a) is rounded before each add (numpy squares first).
__device__ __forceinline__ float np_sumsq64(const float* __restrict__ a) {
#pragma clang fp contract(off)
    float r0 = a[0] * a[0], r1 = a[1] * a[1], r2 = a[2] * a[2], r3 = a[3] * a[3];
    float r4 = a[4] * a[4], r5 = a[5] * a[5], r6 = a[6] * a[6], r7 = a[7] * a[7];
    for (int i = 8; i < 64; i += 8) {
        r0 += a[i + 0] * a[i + 0];
        r1 += a[i + 1] * a[i + 1];
        r2 += a[i + 2] * a[i + 2];
        r3 += a[i + 3] * a[i + 3];
        r4 += a[i + 4] * a[i + 4];
        r5 += a[i + 5] * a[i + 5];
        r6 += a[i + 6] * a[i + 6];
        r7 += a[i + 7] * a[i + 7];
    }
    return ((r0 + r1) + (r2 + r3)) + ((r4 + r5) + (r6 + r7));
}

__global__ __launch_bounds__(256) void vq_init(const float* __restrict__ emb,
                                               float* __restrict__ ws) {
    int t = blockIdx.x * 256 + threadIdx.x;
    if (t < WS_ZERO_LEN) ws[WS_CNT + t] = 0.0f;
    if (t < NUM_K) ws[WS_SE + t] = np_sumsq64(emb + t * DIM);
}

__global__ __launch_bounds__(256) void vq_main(const float* __restrict__ in,
                                               const float* __restrict__ emb,
                                               float* __restrict__ out,
                                               float* __restrict__ ws) {
    const int n  = blockIdx.x * 256 + threadIdx.x;   // pixel id
    const int b  = n >> 12;
    const int hw = n & 4095;

    // flat[n, d] = inputs[b, d, h, w]
    const float* xp = in + (size_t)b * (DIM * HWSZ) + hw;
    float x[DIM];
#pragma unroll
    for (int d = 0; d < DIM; ++d) x[d] = xp[(size_t)d * HWSZ];

    // Sx = np.sum(flat*flat, axis=1) — numpy pairwise emulation
    float Sx;
    {
#pragma clang fp contract(off)
        float r0 = x[0] * x[0], r1 = x[1] * x[1], r2 = x[2] * x[2], r3 = x[3] * x[3];
        float r4 = x[4] * x[4], r5 = x[5] * x[5], r6 = x[6] * x[6], r7 = x[7] * x[7];
#pragma unroll
        for (int i = 8; i < 64; i += 8) {
            r0 += x[i + 0] * x[i + 0];
            r1 += x[i + 1] * x[i + 1];
            r2 += x[i + 2] * x[i + 2];
            r3 += x[i + 3] * x[i + 3];
            r4 += x[i + 4] * x[i + 4];
            r5 += x[i + 5] * x[i + 5];
            r6 += x[i + 6] * x[i + 6];
            r7 += x[i + 7] * x[i + 7];
        }
        Sx = ((r0 + r1) + (r2 + r3)) + ((r4 + r5) + (r6 + r7));
    }

    const float* __restrict__ se = ws + WS_SE;

    // d_k = fl( fl(Sx + Se_k) - 2*dot_k ),  dot_k = sequential fmaf (BLAS k-order)
    float dmin = 3.4e38f;
    int   idx  = 0;
    for (int k = 0; k < NUM_K; ++k) {
        const float* er = emb + (k << 6);     // wave-uniform -> s_load
        float dot = 0.0f;
#pragma unroll
        for (int d = 0; d < DIM; ++d) dot = fmaf(x[d], er[d], dot);
        float dk;
        {
#pragma clang fp contract(off)
            float t = Sx + se[k];
            dk = t - 2.0f * dot;              // 2*dot exact; one rounding
        }
        if (dk < dmin) { dmin = dk; idx = k; }   // strict < keeps first index
    }

    // encoding_indices (as float32)
    out[OUT_IDX + n] = (float)idx;

    // quantized_st == quantized numerically; gather + write [B,C,H,W]
    float*       qp = out + OUT_Q + (size_t)b * (DIM * HWSZ) + hw;
    const float* eq = emb + idx * DIM;
    float*       es = ws + WS_ESUM;
    float lsum = 0.0f;
#pragma unroll
    for (int d = 0; d < DIM; ++d) {
        float e = eq[d];
        qp[(size_t)d * HWSZ] = e;
        float df = e - x[d];
        lsum = fmaf(df, df, lsum);
        atomicAdd(&es[idx * DIM + d], x[d]);   // segment_sum scatter
    }
    atomicAdd(ws + WS_CNT + idx, 1.0f);        // histogram

    // loss partial: wave reduce -> block reduce -> one atomic per block
#pragma unroll
    for (int off = 32; off > 0; off >>= 1) lsum += __shfl_down(lsum, off, 64);
    __shared__ float wred[4];
    const int lane = threadIdx.x & 63, wid = threadIdx.x >> 6;
    if (lane == 0) wred[wid] = lsum;
    __syncthreads();
    if (threadIdx.x == 0) {
        float t = (wred[0] + wred[1]) + (wred[2] + wred[3]);
        atomicAdd(ws + WS_LOSS, t);
    }
}

__global__ __launch_bounds__(1024) void vq_final(const float* __restrict__ ema_cs,
                                                 const float* __restrict__ ema_w,
                                                 float* __restrict__ out,
                                                 const float* __restrict__ ws) {
    const int k = threadIdx.x;
    const float cnt = ws[WS_CNT + k];
    const float ncs = fmaf(0.01f, cnt, 0.99f * ema_cs[k]);
    out[OUT_CS + k] = ncs;

    __shared__ float red[1024];
    red[k] = ncs;
    __syncthreads();
    for (int s = 512; s > 0; s >>= 1) {
        if (k < s) red[k] += red[k + s];
        __syncthreads();
    }
    const float nsum = red[0];
    const float csz  = (ncs + 1e-5f) / (nsum + NUM_K * 1e-5f) * nsum;

#pragma unroll
    for (int d = 0; d < DIM; ++d) {
        float nw = fmaf(0.01f, ws[WS_ESUM + k * DIM + d], 0.99f * ema_w[k * DIM + d]);
        out[OUT_EMAW + k * DIM + d] = nw;
        out[OUT_EMB  + k * DIM + d] = nw / csz;
    }
    if (k == 0) out[OUT_LOSS] = 1.25f * ws[WS_LOSS] / 8388608.0f;
}

extern "C" void kernel_launch(void* const* d_in, const int* in_sizes, int n_in,
                              void* d_out, int out_size, void* d_ws, size_t ws_size,
                              hipStream_t stream) {
    const float* in   = (const float*)d_in[0];
    const float* emb  = (const float*)d_in[1];
    const float* ecs  = (const float*)d_in[2];
    const float* emaw = (const float*)d_in[3];
    float* out = (float*)d_out;
    float* ws  = (float*)d_ws;

    vq_init<<<(WS_ZERO_LEN + 255) / 256, 256, 0, stream>>>(emb, ws);
    vq_main<<<NPIX / 256, 256, 0, stream>>>(in, emb, out, ws);
    vq_final<<<1, 1024, 0, stream>>>(ecs, emaw, out, ws);
}

// Round 3
// 688.258 us; speedup vs baseline: 1.6690x; 1.6690x over previous
//
#include <hip/hip_runtime.h>

#define NUM_K 1024
#define DIM 64
#define HWSZ 4096            // 64*64
#define NPIX 131072          // 32*64*64

// output element offsets (float32 elements)
#define OUT_Q    0u
#define OUT_LOSS 8388608u
#define OUT_IDX  8388609u
#define OUT_CS   8519681u
#define OUT_EMAW 8520705u
#define OUT_EMB  8586241u

// workspace layout (float32 elements)
#define WS_SE    0
#define WS_CNT   1024
#define WS_ESUM  2048
#define WS_LOSS  (2048 + 65536)
#define WS_CSZ   (WS_LOSS + 1)
#define WS_ZERO_LEN (1024 + 65536 + 1)   // counts + esum + loss

#define CHUNK 64
#define NCHUNK (NUM_K / CHUNK)

// numpy pairwise_sum emulation for sum(a[i]^2), n=64 fp32 (proven bit-exact r2)
__device__ __forceinline__ float np_sumsq64(const float* __restrict__ a) {
#pragma clang fp contract(off)
    float r0 = a[0] * a[0], r1 = a[1] * a[1], r2 = a[2] * a[2], r3 = a[3] * a[3];
    float r4 = a[4] * a[4], r5 = a[5] * a[5], r6 = a[6] * a[6], r7 = a[7] * a[7];
    for (int i = 8; i < 64; i += 8) {
        r0 += a[i + 0] * a[i + 0];
        r1 += a[i + 1] * a[i + 1];
        r2 += a[i + 2] * a[i + 2];
        r3 += a[i + 3] * a[i + 3];
        r4 += a[i + 4] * a[i + 4];
        r5 += a[i + 5] * a[i + 5];
        r6 += a[i + 6] * a[i + 6];
        r7 += a[i + 7] * a[i + 7];
    }
    return ((r0 + r1) + (r2 + r3)) + ((r4 + r5) + (r6 + r7));
}

__global__ __launch_bounds__(256) void vq_init(const float* __restrict__ emb,
                                               float* __restrict__ ws) {
    int t = blockIdx.x * 256 + threadIdx.x;
    if (t < WS_ZERO_LEN) ws[WS_CNT + t] = 0.0f;
    if (t < NUM_K) ws[WS_SE + t] = np_sumsq64(emb + t * DIM);
}

__global__ __launch_bounds__(256, 2) void vq_main(const float* __restrict__ in,
                                                  const float* __restrict__ emb,
                                                  float* __restrict__ out,
                                                  float* __restrict__ ws) {
    // pool: E double-buffer (2x 16KB) during scan; x-transpose (128x68 f) after
    __shared__ __align__(16) float pool[8704];
    __shared__ float seT[2][CHUNK];
    __shared__ int   idxL[256];
    __shared__ float wred[4];

    const int t  = threadIdx.x;
    const int n  = blockIdx.x * 256 + t;
    const int b  = n >> 12;
    const int hw = n & 4095;
    const int lane = t & 63, wid = t >> 6;

    // x[d] = inputs[b, d, hw]  (coalesced across lanes per d)
    const float* xp = in + (size_t)b * (DIM * HWSZ) + hw;
    float x[DIM];
#pragma unroll
    for (int d = 0; d < DIM; ++d) x[d] = xp[(size_t)d * HWSZ];

    // Sx: numpy pairwise emulation (bit-exact)
    float Sx;
    {
#pragma clang fp contract(off)
        float r0 = x[0] * x[0], r1 = x[1] * x[1], r2 = x[2] * x[2], r3 = x[3] * x[3];
        float r4 = x[4] * x[4], r5 = x[5] * x[5], r6 = x[6] * x[6], r7 = x[7] * x[7];
#pragma unroll
        for (int i = 8; i < 64; i += 8) {
            r0 += x[i + 0] * x[i + 0];
            r1 += x[i + 1] * x[i + 1];
            r2 += x[i + 2] * x[i + 2];
            r3 += x[i + 3] * x[i + 3];
            r4 += x[i + 4] * x[i + 4];
            r5 += x[i + 5] * x[i + 5];
            r6 += x[i + 6] * x[i + 6];
            r7 += x[i + 7] * x[i + 7];
        }
        Sx = ((r0 + r1) + (r2 + r3)) + ((r4 + r5) + (r6 + r7));
    }

    // ---- stage chunk 0 into buf 0 ----
    {
        const float4* s4 = (const float4*)emb;
        float4* d4 = (float4*)pool;
#pragma unroll
        for (int i = 0; i < 4; ++i) d4[t + i * 256] = s4[t + i * 256];
        if (t < CHUNK) seT[0][t] = ws[WS_SE + t];
    }
    __syncthreads();

    float dmin = 3.4e38f;
    int   idx  = 0;
    int   cur  = 0;

    for (int c = 0; c < NCHUNK; ++c) {
        // prefetch next chunk into the other buffer
        if (c + 1 < NCHUNK) {
            const float4* s4 = (const float4*)(emb + ((c + 1) << 12));
            float4* d4 = (float4*)(pool + ((cur ^ 1) << 12));
#pragma unroll
            for (int i = 0; i < 4; ++i) d4[t + i * 256] = s4[t + i * 256];
            if (t < CHUNK) seT[cur ^ 1][t] = ws[WS_SE + ((c + 1) << 6) + t];
        }
        // compute on current chunk (E reads are wave-uniform LDS broadcasts)
        const float* eb = pool + (cur << 12);
        const float* sb = seT[cur];
        const int k0 = c << 6;
        for (int q = 0; q < CHUNK; ++q) {
            const float* er = eb + (q << 6);
            float dot = 0.0f;
#pragma unroll
            for (int d = 0; d < DIM; ++d) dot = fmaf(x[d], er[d], dot);  // exact seq chain
            float dk;
            {
#pragma clang fp contract(off)
                float tt = Sx + sb[q];
                dk = tt - 2.0f * dot;
            }
            if (dk < dmin) { dmin = dk; idx = k0 + q; }   // strict <, ascending k
        }
        __syncthreads();
        cur ^= 1;
    }

    // ---- epilogue ----
    out[OUT_IDX + n] = (float)idx;
    idxL[t] = idx;

    // quantized gather + write + loss partial
    float* qp = out + OUT_Q + (size_t)b * (DIM * HWSZ) + hw;
    const float* eq = emb + (idx << 6);
    float lsum = 0.0f;
#pragma unroll
    for (int d = 0; d < DIM; ++d) {
        float e = eq[d];
        qp[(size_t)d * HWSZ] = e;
        float df = e - x[d];
        lsum = fmaf(df, df, lsum);
    }
    atomicAdd(ws + WS_CNT + idx, 1.0f);

#pragma unroll
    for (int off = 32; off > 0; off >>= 1) lsum += __shfl_down(lsum, off, 64);
    if (lane == 0) wred[wid] = lsum;
    __syncthreads();   // also guards idxL + pool reuse
    if (t == 0) atomicAdd(ws + WS_LOSS, (wred[0] + wred[1]) + (wred[2] + wred[3]));

    // esum scatter: transpose x through LDS -> one coalesced 256B atomic per pixel
    float* es = ws + WS_ESUM;
    for (int h = 0; h < 2; ++h) {
        if ((t >> 7) == h) {
            const int r = t & 127;
            float4* row = (float4*)(pool + r * 68);
#pragma unroll
            for (int i = 0; i < 16; ++i)
                row[i] = make_float4(x[4 * i], x[4 * i + 1], x[4 * i + 2], x[4 * i + 3]);
        }
        __syncthreads();
#pragma unroll 1
        for (int j = 0; j < 32; ++j) {
            const int r  = (wid << 5) + j;
            const int id = idxL[(h << 7) + r];
            atomicAdd(es + (id << 6) + lane, pool[r * 68 + lane]);
        }
        __syncthreads();
    }
}

__global__ __launch_bounds__(1024) void vq_final_a(const float* __restrict__ ema_cs,
                                                   float* __restrict__ out,
                                                   float* __restrict__ ws) {
    const int k = threadIdx.x;
    const float cnt = ws[WS_CNT + k];
    const float ncs = fmaf(0.01f, cnt, 0.99f * ema_cs[k]);
    out[OUT_CS + k] = ncs;

    __shared__ float red[1024];
    red[k] = ncs;
    __syncthreads();
    for (int s = 512; s > 0; s >>= 1) {
        if (k < s) red[k] += red[k + s];
        __syncthreads();
    }
    const float nsum = red[0];
    ws[WS_CSZ + k] = (ncs + 1e-5f) / (nsum + NUM_K * 1e-5f) * nsum;
}

__global__ __launch_bounds__(256) void vq_final_b(const float* __restrict__ ema_w,
                                                  float* __restrict__ out,
                                                  float* __restrict__ ws) {
    const int i = blockIdx.x * 256 + threadIdx.x;   // 65536 = k*64+d
    const int k = i >> 6;
    const float nw = fmaf(0.01f, ws[WS_ESUM + i], 0.99f * ema_w[i]);
    out[OUT_EMAW + i] = nw;
    out[OUT_EMB  + i] = nw / ws[WS_CSZ + k];
    if (i == 0) out[OUT_LOSS] = 1.25f * ws[WS_LOSS] * (1.0f / 8388608.0f);
}

extern "C" void kernel_launch(void* const* d_in, const int* in_sizes, int n_in,
                              void* d_out, int out_size, void* d_ws, size_t ws_size,
                              hipStream_t stream) {
    const float* in   = (const float*)d_in[0];
    const float* emb  = (const float*)d_in[1];
    const float* ecs  = (const float*)d_in[2];
    const float* emaw = (const float*)d_in[3];
    float* out = (float*)d_out;
    float* ws  = (float*)d_ws;

    vq_init<<<(WS_ZERO_LEN + 255) / 256, 256, 0, stream>>>(emb, ws);
    vq_main<<<NPIX / 256, 256, 0, stream>>>(in, emb, out, ws);
    vq_final_a<<<1, 1024, 0, stream>>>(ecs, out, ws);
    vq_final_b<<<256, 256, 0, stream>>>(emaw, out, ws);
}

// Round 4
// 322.348 us; speedup vs baseline: 3.5635x; 2.1351x over previous
//
#include <hip/hip_runtime.h>

#define NUM_K 1024
#define DIM 64
#define HWSZ 4096            // 64*64
#define NPIX 131072          // 32*64*64

// output element offsets (float32 elements)
#define OUT_Q    0u
#define OUT_LOSS 8388608u
#define OUT_IDX  8388609u
#define OUT_CS   8519681u
#define OUT_EMAW 8520705u
#define OUT_EMB  8586241u

// workspace layout (float32 elements)
#define WS_SE    0
#define WS_CNT   1024
#define WS_ESUM  2048
#define WS_LOSS  67584
#define WS_CSZ   67585
#define WS_SX    69632                  // 131072 floats
#define WS_ET    200704                 // 65536 floats, ET[d][k]
#define WS_ZERO_BEG 1024
#define WS_ZERO_LEN 66561               // cnt + esum + loss

// tiling
#define PIXB  128      // pixels per block
#define KTILE 64       // codes per pass
#define NPASS (NUM_K / KTILE)
#define TM 8           // pixels per thread
#define TN 4           // codes per thread
#define XPAD 132       // xT row stride (16B-aligned: 132*4=528)

// numpy pairwise_sum emulation for sum(a[i]^2), n=64 fp32 (bit-exact, proven r2/r3)
__device__ __forceinline__ float np_sumsq64(const float* __restrict__ a) {
#pragma clang fp contract(off)
    float r0 = a[0] * a[0], r1 = a[1] * a[1], r2 = a[2] * a[2], r3 = a[3] * a[3];
    float r4 = a[4] * a[4], r5 = a[5] * a[5], r6 = a[6] * a[6], r7 = a[7] * a[7];
    for (int i = 8; i < 64; i += 8) {
        r0 += a[i + 0] * a[i + 0];
        r1 += a[i + 1] * a[i + 1];
        r2 += a[i + 2] * a[i + 2];
        r3 += a[i + 3] * a[i + 3];
        r4 += a[i + 4] * a[i + 4];
        r5 += a[i + 5] * a[i + 5];
        r6 += a[i + 6] * a[i + 6];
        r7 += a[i + 7] * a[i + 7];
    }
    return ((r0 + r1) + (r2 + r3)) + ((r4 + r5) + (r6 + r7));
}

__global__ __launch_bounds__(256) void vq_init(const float* __restrict__ emb,
                                               float* __restrict__ ws) {
    const int t = blockIdx.x * 256 + threadIdx.x;
    if (t < WS_ZERO_LEN) ws[WS_ZERO_BEG + t] = 0.0f;
    if (t < 65536) {                    // ET[d][k] = emb[k][d]  (write-coalesced)
        const int d = t >> 10, k = t & 1023;
        ws[WS_ET + t] = emb[k * DIM + d];
    }
    if (t < NUM_K) ws[WS_SE + t] = np_sumsq64(emb + t * DIM);
}

__global__ __launch_bounds__(256) void vq_sx(const float* __restrict__ in,
                                             float* __restrict__ ws) {
    const int n  = blockIdx.x * 256 + threadIdx.x;
    const int b  = n >> 12, hw = n & 4095;
    const float* xp = in + (size_t)b * (DIM * HWSZ) + hw;
    float x[DIM];
#pragma unroll
    for (int d = 0; d < DIM; ++d) x[d] = xp[(size_t)d * HWSZ];
    ws[WS_SX + n] = np_sumsq64(x);
}

__global__ __launch_bounds__(256, 3) void vq_main(const float* __restrict__ in,
                                                  const float* __restrict__ emb,
                                                  float* __restrict__ out,
                                                  float* __restrict__ ws) {
    __shared__ __align__(16) float xT[DIM * XPAD];   // 33792 B
    __shared__ __align__(16) float eT[DIM * KTILE];  // 16384 B (reused as reduce scratch)
    __shared__ __align__(16) float SxL[PIXB];
    __shared__ float redV[2][PIXB];
    __shared__ int   redI[2][PIXB];
    __shared__ float wred[4];

    const int t   = threadIdx.x;
    const int col = t & 15;          // pixel group
    const int row = t >> 4;          // code group
    const int p0  = col << 3;        // first of TM pixels
    const int bid = blockIdx.x;
    const int b   = bid >> 5;
    const int hw0 = (bid & 31) << 7;
    const int n0  = bid << 7;        // first pixel id

    // ---- stage xT[d][p] from in[b][d][hw0+p] (no transpose needed) ----
    {
        const float4* s4 = (const float4*)(in + (size_t)b * (DIM * HWSZ) + hw0);
#pragma unroll
        for (int i = 0; i < 8; ++i) {
            const int fi = t + i * 256;          // 2048 float4s
            const int r = fi >> 5, j = fi & 31;
            *(float4*)&xT[r * XPAD + j * 4] = s4[(size_t)r * (HWSZ / 4) + j];
        }
        if (t < 32) ((float4*)SxL)[t] = ((const float4*)(ws + WS_SX + n0))[t];
        // stage eT for pass 0
        const float4* ET4 = (const float4*)(ws + WS_ET);
#pragma unroll
        for (int i = 0; i < 4; ++i) {
            const int fi = t + i * 256;          // 1024 float4s
            const int r = fi >> 4, j = fi & 15;
            ((float4*)eT)[fi] = ET4[r * 256 + j];
        }
    }
    __syncthreads();

    float Sxr[TM];
#pragma unroll
    for (int i = 0; i < TM; ++i) Sxr[i] = SxL[p0 + i];

    float dmin[TM];
    int   idxm[TM];
#pragma unroll
    for (int i = 0; i < TM; ++i) { dmin[i] = 3.4e38f; idxm[i] = 0; }

    for (int c = 0; c < NPASS; ++c) {
        const float4 se4 = *(const float4*)(ws + WS_SE + (c << 6) + (row << 2));
        float acc[TM][TN];
#pragma unroll
        for (int i = 0; i < TM; ++i)
#pragma unroll
            for (int j = 0; j < TN; ++j) acc[i][j] = 0.0f;

#pragma unroll 4
        for (int d = 0; d < DIM; ++d) {
            const float4 xa = *(const float4*)&xT[d * XPAD + p0];
            const float4 xb = *(const float4*)&xT[d * XPAD + p0 + 4];
            const float4 ef = *(const float4*)&eT[(d << 6) + (row << 2)];
            const float xs[TM] = {xa.x, xa.y, xa.z, xa.w, xb.x, xb.y, xb.z, xb.w};
            const float es[TN] = {ef.x, ef.y, ef.z, ef.w};
#pragma unroll
            for (int i = 0; i < TM; ++i)
#pragma unroll
                for (int j = 0; j < TN; ++j)
                    acc[i][j] = fmaf(xs[i], es[j], acc[i][j]);  // seq chain, d ascending
        }

        // dk = fl( fl(Sx+Se) - 2*dot ); strict <, k ascending per thread
        const int kbase = (c << 6) + (row << 2);
        const float ses[TN] = {se4.x, se4.y, se4.z, se4.w};
#pragma unroll
        for (int i = 0; i < TM; ++i) {
#pragma unroll
            for (int j = 0; j < TN; ++j) {
#pragma clang fp contract(off)
                float tt = Sxr[i] + ses[j];
                float dk = tt - 2.0f * acc[i][j];
                if (dk < dmin[i]) { dmin[i] = dk; idxm[i] = kbase + j; }
            }
        }

        __syncthreads();
        if (c + 1 < NPASS) {   // restage eT while min-update of other waves runs
            const float4* ET4 = (const float4*)(ws + WS_ET);
#pragma unroll
            for (int i = 0; i < 4; ++i) {
                const int fi = t + i * 256;
                const int r = fi >> 4, j = fi & 15;
                ((float4*)eT)[fi] = ET4[r * 256 + ((c + 1) << 4) + j];
            }
        }
        __syncthreads();
    }

    // ---- argmin reduction across the 16 code-rows (eT reused as scratch) ----
    float* vals = eT;                       // [16][128]
    int*   idxs = (int*)(eT + 2048);        // [16][128]
#pragma unroll
    for (int i = 0; i < TM; ++i) {
        vals[row * PIXB + p0 + i] = dmin[i];
        idxs[row * PIXB + p0 + i] = idxm[i];
    }
    __syncthreads();
    {
        const int half = t >> 7, p = t & 127;
        float bv = vals[(half * 8) * PIXB + p];
        int   bi = idxs[(half * 8) * PIXB + p];
#pragma unroll
        for (int r = 1; r < 8; ++r) {
            const float v = vals[(half * 8 + r) * PIXB + p];
            const int  id = idxs[(half * 8 + r) * PIXB + p];
            if (v < bv || (v == bv && id < bi)) { bv = v; bi = id; }
        }
        redV[half][p] = bv; redI[half][p] = bi;
    }
    __syncthreads();
    if (t < PIXB) {
        float v0 = redV[0][t]; int i0 = redI[0][t];
        const float v1 = redV[1][t]; const int i1 = redI[1][t];
        if (v1 < v0 || (v1 == v0 && i1 < i0)) { v0 = v1; i0 = i1; }
        redI[0][t] = i0;
        out[OUT_IDX + n0 + t] = (float)i0;
    }
    __syncthreads();

    // ---- epilogue: quantized write + loss + esum/count atomics ----
    const int ph = t & 127, dh = t >> 7;    // pixel, d-half
    const int id = redI[0][ph];
    float* qp = out + OUT_Q + (size_t)b * (DIM * HWSZ) + hw0 + ph;
    const float4* eq4 = (const float4*)(emb + (id << 6) + dh * 32);
    float lsum = 0.0f;
#pragma unroll
    for (int i = 0; i < 8; ++i) {
        const float4 e4 = eq4[i];
        const float ev[4] = {e4.x, e4.y, e4.z, e4.w};
#pragma unroll
        for (int q = 0; q < 4; ++q) {
            const int d = dh * 32 + i * 4 + q;
            qp[(size_t)d * HWSZ] = ev[q];
            const float df = ev[q] - xT[d * XPAD + ph];
            lsum = fmaf(df, df, lsum);
        }
    }
    if (t < PIXB) atomicAdd(ws + WS_CNT + id, 1.0f);

    const int lane = t & 63, wid = t >> 6;
#pragma unroll
    for (int off = 32; off > 0; off >>= 1) lsum += __shfl_down(lsum, off, 64);
    if (lane == 0) wred[wid] = lsum;
    __syncthreads();
    if (t == 0) atomicAdd(ws + WS_LOSS, (wred[0] + wred[1]) + (wred[2] + wred[3]));

    // esum: one coalesced 256B atomic burst per pixel
    float* es = ws + WS_ESUM;
#pragma unroll 1
    for (int j = 0; j < 32; ++j) {
        const int p  = (wid << 5) + j;
        const int pid = redI[0][p];
        atomicAdd(es + (pid << 6) + lane, xT[lane * XPAD + p]);
    }
}

__global__ __launch_bounds__(1024) void vq_final_a(const float* __restrict__ ema_cs,
                                                   float* __restrict__ out,
                                                   float* __restrict__ ws) {
    const int k = threadIdx.x;
    const float cnt = ws[WS_CNT + k];
    const float ncs = fmaf(0.01f, cnt, 0.99f * ema_cs[k]);
    out[OUT_CS + k] = ncs;

    __shared__ float red[1024];
    red[k] = ncs;
    __syncthreads();
    for (int s = 512; s > 0; s >>= 1) {
        if (k < s) red[k] += red[k + s];
        __syncthreads();
    }
    const float nsum = red[0];
    ws[WS_CSZ + k] = (ncs + 1e-5f) / (nsum + NUM_K * 1e-5f) * nsum;
}

__global__ __launch_bounds__(256) void vq_final_b(const float* __restrict__ ema_w,
                                                  float* __restrict__ out,
                                                  float* __restrict__ ws) {
    const int i = blockIdx.x * 256 + threadIdx.x;
    const int k = i >> 6;
    const float nw = fmaf(0.01f, ws[WS_ESUM + i], 0.99f * ema_w[i]);
    out[OUT_EMAW + i] = nw;
    out[OUT_EMB  + i] = nw / ws[WS_CSZ + k];
    if (i == 0) out[OUT_LOSS] = 1.25f * ws[WS_LOSS] * (1.0f / 8388608.0f);
}

extern "C" void kernel_launch(void* const* d_in, const int* in_sizes, int n_in,
                              void* d_out, int out_size, void* d_ws, size_t ws_size,
                              hipStream_t stream) {
    const float* in   = (const float*)d_in[0];
    const float* emb  = (const float*)d_in[1];
    const float* ecs  = (const float*)d_in[2];
    const float* emaw = (const float*)d_in[3];
    float* out = (float*)d_out;
    float* ws  = (float*)d_ws;

    vq_init<<<261, 256, 0, stream>>>(emb, ws);
    vq_sx<<<NPIX / 256, 256, 0, stream>>>(in, ws);
    vq_main<<<NPIX / PIXB, 256, 0, stream>>>(in, emb, out, ws);
    vq_final_a<<<1, 1024, 0, stream>>>(ecs, out, ws);
    vq_final_b<<<256, 256, 0, stream>>>(emaw, out, ws);
}

// Round 5
// 302.209 us; speedup vs baseline: 3.8010x; 1.0666x over previous
//
#include <hip/hip_runtime.h>

#define NUM_K 1024
#define DIM 64
#define HWSZ 4096            // 64*64
#define NPIX 131072          // 32*64*64

// output element offsets (float32 elements)
#define OUT_Q    0u
#define OUT_LOSS 8388608u
#define OUT_IDX  8388609u
#define OUT_CS   8519681u
#define OUT_EMAW 8520705u
#define OUT_EMB  8586241u

// workspace layout (float32 elements)
#define WS_SE    0
#define WS_CNT   1024
#define WS_ESUM  2048
#define WS_LOSS  67584
#define WS_NSUM  67585
#define WS_ET    69632                  // 65536 floats, ET[d][k]
#define WS_ZERO_BEG 1024
#define WS_ZERO_LEN 66562               // cnt + esum + loss + nsum

// tiling: block = 64 pixels x 128 codes/pass, thread = 4 pixels x 8 codes
#define PIXB  64
#define KTILE 128
#define NPASS (NUM_K / KTILE)
#define TM 4
#define TN 8
#define XSTR 68        // xT row stride in floats (68*4B: 16B-aligned, +4-bank/d rotation)

// numpy pairwise_sum emulation for sum(a[i]^2), n=64 fp32 (bit-exact, proven r2-r4)
__device__ __forceinline__ float np_sumsq64(const float* __restrict__ a) {
#pragma clang fp contract(off)
    float r0 = a[0] * a[0], r1 = a[1] * a[1], r2 = a[2] * a[2], r3 = a[3] * a[3];
    float r4 = a[4] * a[4], r5 = a[5] * a[5], r6 = a[6] * a[6], r7 = a[7] * a[7];
    for (int i = 8; i < 64; i += 8) {
        r0 += a[i + 0] * a[i + 0];
        r1 += a[i + 1] * a[i + 1];
        r2 += a[i + 2] * a[i + 2];
        r3 += a[i + 3] * a[i + 3];
        r4 += a[i + 4] * a[i + 4];
        r5 += a[i + 5] * a[i + 5];
        r6 += a[i + 6] * a[i + 6];
        r7 += a[i + 7] * a[i + 7];
    }
    return ((r0 + r1) + (r2 + r3)) + ((r4 + r5) + (r6 + r7));
}

__global__ __launch_bounds__(256) void vq_init(const float* __restrict__ emb,
                                               float* __restrict__ ws) {
    const int t = blockIdx.x * 256 + threadIdx.x;
    if (t < WS_ZERO_LEN) ws[WS_ZERO_BEG + t] = 0.0f;
    if (t < 65536) {                    // ET[d][k] = emb[k][d]  (write-coalesced)
        const int d = t >> 10, k = t & 1023;
        ws[WS_ET + t] = emb[k * DIM + d];
    }
    if (t < NUM_K) ws[WS_SE + t] = np_sumsq64(emb + t * DIM);
}

__global__ __launch_bounds__(256, 3) void vq_main(const float* __restrict__ in,
                                                  const float* __restrict__ emb,
                                                  float* __restrict__ out,
                                                  float* __restrict__ ws) {
    __shared__ __align__(16) float xT[DIM * XSTR];    // 17408 B
    __shared__ __align__(16) float eT[DIM * KTILE];   // 32768 B (reused as reduce scratch)
    __shared__ float SxL[PIXB];
    __shared__ float wred[4];
    __shared__ int   redI[PIXB];

    const int t   = threadIdx.x;
    const int col = t & 15;          // pixel group (TM=4 pixels)
    const int row = t >> 4;          // code group (TN=8 codes)
    const int p0  = col << 2;
    const int bid = blockIdx.x;
    const int b   = bid >> 6;        // 64 tiles per image
    const int hw0 = (bid & 63) << 6;
    const int n0  = bid << 6;        // first pixel id

    // ---- stage xT[d][p] from in[b][d][hw0+p] ----
    {
        const float4* s4 = (const float4*)(in + (size_t)b * (DIM * HWSZ) + hw0);
#pragma unroll
        for (int i = 0; i < 4; ++i) {
            const int fi = t + i * 256;          // 1024 float4s
            const int r = fi >> 4, j = fi & 15;
            *(float4*)&xT[r * XSTR + j * 4] = s4[(size_t)r * (HWSZ / 4) + j];
        }
        // stage eT for pass 0
        const float4* ET4 = (const float4*)(ws + WS_ET);
#pragma unroll
        for (int i = 0; i < 8; ++i) {
            const int fi = t + i * 256;          // 2048 float4s
            const int r = fi >> 5, q = fi & 31;
            ((float4*)eT)[r * 32 + q] = ET4[r * 256 + q];
        }
    }
    __syncthreads();

    // ---- Sx per pixel (wave 0), numpy pairwise order, bit-exact ----
    if (t < PIXB) {
#pragma clang fp contract(off)
        float r[8];
#pragma unroll
        for (int j = 0; j < 8; ++j) { const float v = xT[j * XSTR + t]; r[j] = v * v; }
#pragma unroll
        for (int i = 8; i < 64; i += 8)
#pragma unroll
            for (int j = 0; j < 8; ++j) { const float v = xT[(i + j) * XSTR + t]; r[j] += v * v; }
        SxL[t] = ((r[0] + r[1]) + (r[2] + r[3])) + ((r[4] + r[5]) + (r[6] + r[7]));
    }
    __syncthreads();

    float Sxr[TM];
#pragma unroll
    for (int i = 0; i < TM; ++i) Sxr[i] = SxL[p0 + i];

    float dmin[TM];
    int   idxm[TM];
#pragma unroll
    for (int i = 0; i < TM; ++i) { dmin[i] = 3.4e38f; idxm[i] = 0; }

    for (int c = 0; c < NPASS; ++c) {
        const float4 se0 = *(const float4*)(ws + WS_SE + (c << 7) + (row << 3));
        const float4 se1 = *(const float4*)(ws + WS_SE + (c << 7) + (row << 3) + 4);

        float acc[TM][TN];
#pragma unroll
        for (int i = 0; i < TM; ++i)
#pragma unroll
            for (int j = 0; j < TN; ++j) acc[i][j] = 0.0f;

#pragma unroll 4
        for (int d = 0; d < DIM; ++d) {
            const float4 xa = *(const float4*)&xT[d * XSTR + p0];
            const float4 e0 = *(const float4*)&eT[(d << 7) + (row << 3)];
            const float4 e1 = *(const float4*)&eT[(d << 7) + (row << 3) + 4];
            const float xs[TM] = {xa.x, xa.y, xa.z, xa.w};
            const float es[TN] = {e0.x, e0.y, e0.z, e0.w, e1.x, e1.y, e1.z, e1.w};
#pragma unroll
            for (int i = 0; i < TM; ++i)
#pragma unroll
                for (int j = 0; j < TN; ++j)
                    acc[i][j] = fmaf(xs[i], es[j], acc[i][j]);  // seq chain, d ascending
        }

        // dk = fl( fl(Sx+Se) - 2*dot ); strict <, k ascending per thread
        const int kbase = (c << 7) + (row << 3);
        const float ses[TN] = {se0.x, se0.y, se0.z, se0.w, se1.x, se1.y, se1.z, se1.w};
#pragma unroll
        for (int i = 0; i < TM; ++i) {
#pragma unroll
            for (int j = 0; j < TN; ++j) {
#pragma clang fp contract(off)
                const float tt = Sxr[i] + ses[j];
                const float dk = tt - 2.0f * acc[i][j];
                if (dk < dmin[i]) { dmin[i] = dk; idxm[i] = kbase + j; }
            }
        }

        __syncthreads();
        if (c + 1 < NPASS) {           // restage eT for next pass
            const float4* ET4 = (const float4*)(ws + WS_ET);
#pragma unroll
            for (int i = 0; i < 8; ++i) {
                const int fi = t + i * 256;
                const int r = fi >> 5, q = fi & 31;
                ((float4*)eT)[r * 32 + q] = ET4[r * 256 + ((c + 1) << 5) + q];
            }
        }
        __syncthreads();
    }

    // ---- argmin reduction across 16 code-rows (eT reused as scratch) ----
    float* vals = eT;                       // [16][64]
    int*   idxs = (int*)(eT + 1024);        // [16][64]
#pragma unroll
    for (int i = 0; i < TM; ++i) {
        vals[row * PIXB + p0 + i] = dmin[i];
        idxs[row * PIXB + p0 + i] = idxm[i];
    }
    __syncthreads();
    if (t < PIXB) {
        float bv = vals[t];
        int   bi = idxs[t];
#pragma unroll
        for (int r = 1; r < 16; ++r) {
            const float v = vals[r * PIXB + t];
            const int  id = idxs[r * PIXB + t];
            if (v < bv || (v == bv && id < bi)) { bv = v; bi = id; }
        }
        redI[t] = bi;
        out[OUT_IDX + n0 + t] = (float)bi;
    }
    __syncthreads();

    // ---- epilogue: quantized write + loss + count/esum atomics ----
    const int ph = t & 63, dh = t >> 6;     // pixel, d-quarter (16 d's)
    const int id = redI[ph];
    float* qp = out + OUT_Q + (size_t)b * (DIM * HWSZ) + hw0 + ph;
    const float4* eq4 = (const float4*)(emb + (id << 6) + (dh << 4));
    float lsum = 0.0f;
#pragma unroll
    for (int i = 0; i < 4; ++i) {
        const float4 e4 = eq4[i];
        const float ev[4] = {e4.x, e4.y, e4.z, e4.w};
#pragma unroll
        for (int q = 0; q < 4; ++q) {
            const int d = (dh << 4) + i * 4 + q;
            qp[(size_t)d * HWSZ] = ev[q];
            const float df = ev[q] - xT[d * XSTR + ph];
            lsum = fmaf(df, df, lsum);
        }
    }

    const int lane = t & 63, wid = t >> 6;
    if (lane < 16) atomicAdd(ws + WS_CNT + redI[(wid << 4) + lane], 1.0f);

#pragma unroll
    for (int off = 32; off > 0; off >>= 1) lsum += __shfl_down(lsum, off, 64);
    if (lane == 0) wred[wid] = lsum;
    __syncthreads();
    if (t == 0) atomicAdd(ws + WS_LOSS, (wred[0] + wred[1]) + (wred[2] + wred[3]));

    // esum: one coalesced 256B atomic burst per pixel (16 pixels per wave)
    float* es = ws + WS_ESUM;
#pragma unroll 1
    for (int j = 0; j < 16; ++j) {
        const int p  = (wid << 4) + j;
        const int pid = redI[p];
        atomicAdd(es + (pid << 6) + lane, xT[lane * XSTR + p]);
    }
}

__global__ __launch_bounds__(256) void vq_cs(const float* __restrict__ ema_cs,
                                             float* __restrict__ out,
                                             float* __restrict__ ws) {
    const int k = blockIdx.x * 256 + threadIdx.x;   // grid 4 -> k < 1024
    const float ncs = fmaf(0.01f, ws[WS_CNT + k], 0.99f * ema_cs[k]);
    out[OUT_CS + k] = ncs;
    float s = ncs;
#pragma unroll
    for (int off = 32; off > 0; off >>= 1) s += __shfl_down(s, off, 64);
    if ((threadIdx.x & 63) == 0) atomicAdd(ws + WS_NSUM, s);
}

__global__ __launch_bounds__(256) void vq_final_b(const float* __restrict__ ema_w,
                                                  float* __restrict__ out,
                                                  float* __restrict__ ws) {
    const int i = blockIdx.x * 256 + threadIdx.x;   // 65536
    const int k = i >> 6;
    const float nsum = ws[WS_NSUM];
    const float ncs  = out[OUT_CS + k];
    const float csz  = (ncs + 1e-5f) / (nsum + 1024.0f * 1e-5f) * nsum;
    const float nw   = fmaf(0.01f, ws[WS_ESUM + i], 0.99f * ema_w[i]);
    out[OUT_EMAW + i] = nw;
    out[OUT_EMB  + i] = nw / csz;
    if (i == 0) out[OUT_LOSS] = 1.25f * ws[WS_LOSS] * (1.0f / 8388608.0f);
}

extern "C" void kernel_launch(void* const* d_in, const int* in_sizes, int n_in,
                              void* d_out, int out_size, void* d_ws, size_t ws_size,
                              hipStream_t stream) {
    const float* in   = (const float*)d_in[0];
    const float* emb  = (const float*)d_in[1];
    const float* ecs  = (const float*)d_in[2];
    const float* emaw = (const float*)d_in[3];
    float* out = (float*)d_out;
    float* ws  = (float*)d_ws;

    vq_init<<<261, 256, 0, stream>>>(emb, ws);
    vq_main<<<NPIX / PIXB, 256, 0, stream>>>(in, emb, out, ws);
    vq_cs<<<4, 256, 0, stream>>>(ecs, out, ws);
    vq_final_b<<<256, 256, 0, stream>>>(emaw, out, ws);
}

// Round 6
// 242.006 us; speedup vs baseline: 4.7466x; 1.2488x over previous
//
#include <hip/hip_runtime.h>

#define NUM_K 1024
#define DIM 64
#define HWSZ 4096            // 64*64
#define NPIX 131072          // 32*64*64

// output element offsets (float32 elements)
#define OUT_Q    0u
#define OUT_LOSS 8388608u
#define OUT_IDX  8388609u
#define OUT_CS   8519681u
#define OUT_EMAW 8520705u
#define OUT_EMB  8586241u

// workspace layout (float32 elements)
#define WS_SE    0          // 1024
#define WS_CNT   1024       // 1024
#define WS_ESUM  2048       // 65536
#define WS_LOSS  67584
#define WS_NSUM  67585
#define WS_SEF   67840      // 16384 f  (f32x4 per (ct,lane): Se in C/D fragment order)
#define WS_EBF   84224      // 32768 u32 (8192 uint4: E bf16 fragments)
#define WS_ZERO_BEG 1024
#define WS_ZERO_LEN 66562   // cnt + esum + loss + nsum

#define MARGIN 1e-3f

using bf16x8 = __attribute__((ext_vector_type(8))) short;
using f32x4  = __attribute__((ext_vector_type(4))) float;

// f32 -> bf16 round-to-nearest-even (internal approximation only)
__device__ __forceinline__ unsigned short f2bf(float f) {
    unsigned u = __float_as_uint(f);
    u += 0x7FFFu + ((u >> 16) & 1u);
    return (unsigned short)(u >> 16);
}

// numpy pairwise_sum emulation for sum(a[i]^2), n=64 fp32, contiguous (bit-exact r2-r5)
__device__ __forceinline__ float np_sumsq64(const float* __restrict__ a) {
#pragma clang fp contract(off)
    float r0 = a[0] * a[0], r1 = a[1] * a[1], r2 = a[2] * a[2], r3 = a[3] * a[3];
    float r4 = a[4] * a[4], r5 = a[5] * a[5], r6 = a[6] * a[6], r7 = a[7] * a[7];
    for (int i = 8; i < 64; i += 8) {
        r0 += a[i + 0] * a[i + 0];
        r1 += a[i + 1] * a[i + 1];
        r2 += a[i + 2] * a[i + 2];
        r3 += a[i + 3] * a[i + 3];
        r4 += a[i + 4] * a[i + 4];
        r5 += a[i + 5] * a[i + 5];
        r6 += a[i + 6] * a[i + 6];
        r7 += a[i + 7] * a[i + 7];
    }
    return ((r0 + r1) + (r2 + r3)) + ((r4 + r5) + (r6 + r7));
}

// same, strided source (xF column)
__device__ __forceinline__ float np_sumsq64_s(const float* __restrict__ a, int stride) {
#pragma clang fp contract(off)
    float r[8];
#pragma unroll
    for (int j = 0; j < 8; ++j) { const float v = a[j * stride]; r[j] = v * v; }
#pragma unroll
    for (int i = 8; i < 64; i += 8)
#pragma unroll
        for (int j = 0; j < 8; ++j) { const float v = a[(i + j) * stride]; r[j] += v * v; }
    return ((r[0] + r[1]) + (r[2] + r[3])) + ((r[4] + r[5]) + (r[6] + r[7]));
}

__global__ __launch_bounds__(256) void vq_init(const float* __restrict__ emb,
                                               float* __restrict__ ws) {
    const int t = blockIdx.x * 256 + threadIdx.x;
    if (t < WS_ZERO_LEN) ws[WS_ZERO_BEG + t] = 0.0f;
    if (t < NUM_K) ws[WS_SE + t] = np_sumsq64(emb + t * DIM);
    if (t < 4096) {          // SeF[ct][lane] = { Se[ct*16 + 4*(lane>>4) + r] }
        const int ct = t >> 6, g = (t & 63) >> 4;
        f32x4 v;
#pragma unroll
        for (int r = 0; r < 4; ++r) v[r] = np_sumsq64(emb + (ct * 16 + g * 4 + r) * DIM);
        ((f32x4*)(ws + WS_SEF))[t] = v;
    }
    if (t < 8192) {          // EbF[ct][h][lane] : code=ct*16+(lane&15), d=h*32+8*(lane>>4)+e
        const int ct = t >> 7, h = (t >> 6) & 1, ln = t & 63;
        const int code = ct * 16 + (ln & 15), g = ln >> 4;
        const float* er = emb + code * DIM + h * 32 + g * 8;
        unsigned s[8];
#pragma unroll
        for (int e = 0; e < 8; ++e) s[e] = f2bf(er[e]);
        uint4 v = make_uint4(s[0] | (s[1] << 16), s[2] | (s[3] << 16),
                             s[4] | (s[5] << 16), s[6] | (s[7] << 16));
        ((uint4*)(ws + WS_EBF))[t] = v;
    }
}

__global__ __launch_bounds__(256) void vq_main(const float* __restrict__ in,
                                               const float* __restrict__ emb,
                                               float* __restrict__ out,
                                               float* __restrict__ ws) {
    __shared__ __align__(16) float xF[DIM * 132];     // 33792 B: [d][128 px half], pad 132
    __shared__ int            cnt_l[256];
    __shared__ unsigned short cand[256 * 12];
    __shared__ int            bk[256];
    __shared__ float          wred[4];

    const int t    = threadIdx.x;
    const int lane = t & 63, w = t >> 6;
    const int g    = lane >> 4, cpix = lane & 15;
    const int bid  = blockIdx.x;
    const int b    = bid >> 4;                 // 16 blocks per image
    const int hw0  = (bid & 15) << 8;          // 256 pixels per block
    const int n0   = bid << 8;

    const float* inb = in + (size_t)b * (DIM * HWSZ);

    // ---- stage half hh (128 pixels x 64 d) into xF ----
#define STAGE(hh)                                                            \
    {                                                                        \
        const float4* s4 = (const float4*)(inb + hw0 + (hh) * 128);          \
        _Pragma("unroll")                                                    \
        for (int i = 0; i < 8; ++i) {                                        \
            const int fi = t + i * 256;                                      \
            const int d = fi >> 5, p4 = fi & 31;                             \
            *(float4*)&xF[d * 132 + p4 * 4] = s4[(size_t)d * 1024 + p4];     \
        }                                                                    \
    }

    bf16x8 Bfr[4][2];
    float  Sx = 0.0f;

    // build B-frags for this wave's 4 pixel-tiles from the staged half.
    // consistent slot->d rule (d = h*32 + 8g + e) on BOTH A and B makes the
    // MFMA dot permutation-invariant to the HW k-layout.
#define BUILD(plbase)                                                        \
    {                                                                        \
        _Pragma("unroll")                                                    \
        for (int tt = 0; tt < 4; ++tt) {                                     \
            const int p = (plbase) + tt * 16 + cpix;                         \
            _Pragma("unroll")                                                \
            for (int h = 0; h < 2; ++h) {                                    \
                bf16x8 v;                                                    \
                _Pragma("unroll")                                            \
                for (int e = 0; e < 8; ++e)                                  \
                    v[e] = (short)f2bf(xF[(h * 32 + g * 8 + e) * 132 + p]);  \
                Bfr[tt][h] = v;                                              \
            }                                                                \
        }                                                                    \
    }

    STAGE(0);
    if (t < 256) cnt_l[t] = 0;
    __syncthreads();
    if (w < 2) BUILD(w * 64);
    if (t < 128) Sx = np_sumsq64_s(xF + t, 132);
    __syncthreads();
    STAGE(1);
    __syncthreads();
    if (w >= 2) BUILD((w - 2) * 64);
    if (t >= 128) Sx = np_sumsq64_s(xF + (t - 128), 132);
    __syncthreads();

    const bf16x8* Ef = (const bf16x8*)(ws + WS_EBF);
    const f32x4*  Sf = (const f32x4*)(ws + WS_SEF);

    // ---- pass 1: MFMA scan, per-pixel min of s = Se - 2*dot ----
    f32x4 mn[4];
#pragma unroll
    for (int tt = 0; tt < 4; ++tt) { mn[tt][0] = mn[tt][1] = mn[tt][2] = mn[tt][3] = 3.4e38f; }

    for (int ct = 0; ct < 64; ++ct) {
        const bf16x8 A0 = Ef[(ct * 2 + 0) * 64 + lane];
        const bf16x8 A1 = Ef[(ct * 2 + 1) * 64 + lane];
        const f32x4  se = Sf[ct * 64 + lane];
#pragma unroll
        for (int tt = 0; tt < 4; ++tt) {
            f32x4 acc = {0.f, 0.f, 0.f, 0.f};
            acc = __builtin_amdgcn_mfma_f32_16x16x32_bf16(A0, Bfr[tt][0], acc, 0, 0, 0);
            acc = __builtin_amdgcn_mfma_f32_16x16x32_bf16(A1, Bfr[tt][1], acc, 0, 0, 0);
#pragma unroll
            for (int r = 0; r < 4; ++r) {
                const float s = fmaf(-2.0f, acc[r], se[r]);
                mn[tt][r] = fminf(mn[tt][r], s);
            }
        }
    }

    // per-pixel threshold: reduce over regs (in-lane) and lane-quad (xor 16,32)
    float thr[4];
#pragma unroll
    for (int tt = 0; tt < 4; ++tt) {
        float m2 = fminf(fminf(mn[tt][0], mn[tt][1]), fminf(mn[tt][2], mn[tt][3]));
        m2 = fminf(m2, __shfl_xor(m2, 16, 64));
        m2 = fminf(m2, __shfl_xor(m2, 32, 64));
        thr[tt] = m2 + MARGIN;
    }

    // ---- pass 2: bit-identical recompute, collect candidates <= thr ----
    for (int ct = 0; ct < 64; ++ct) {
        const bf16x8 A0 = Ef[(ct * 2 + 0) * 64 + lane];
        const bf16x8 A1 = Ef[(ct * 2 + 1) * 64 + lane];
        const f32x4  se = Sf[ct * 64 + lane];
#pragma unroll
        for (int tt = 0; tt < 4; ++tt) {
            f32x4 acc = {0.f, 0.f, 0.f, 0.f};
            acc = __builtin_amdgcn_mfma_f32_16x16x32_bf16(A0, Bfr[tt][0], acc, 0, 0, 0);
            acc = __builtin_amdgcn_mfma_f32_16x16x32_bf16(A1, Bfr[tt][1], acc, 0, 0, 0);
#pragma unroll
            for (int r = 0; r < 4; ++r) {
                const float s = fmaf(-2.0f, acc[r], se[r]);
                if (s <= thr[tt]) {
                    const int p    = w * 64 + tt * 16 + cpix;
                    const int code = ct * 16 + g * 4 + r;
                    const int sl   = atomicAdd(&cnt_l[p], 1);
                    if (sl < 12) cand[p * 12 + sl] = (unsigned short)code;
                }
            }
        }
    }
    __syncthreads();

    // ---- recheck + epilogue, per 128-pixel half ----
    float lsum = 0.0f;
#define RECHECK_EPI(hh)                                                          \
    if ((t >> 7) == (hh)) {                                                      \
        const int c  = t & 127;                                                  \
        const int cc = min(cnt_l[t], 12);                                        \
        float bd = 3.4e38f; int bi = NUM_K;                                      \
        for (int j = 0; j < cc; ++j) {                                           \
            const int cd = cand[t * 12 + j];                                     \
            const float4* er = (const float4*)(emb + cd * DIM);                  \
            float dot = 0.0f;                                                    \
            _Pragma("unroll")                                                    \
            for (int i = 0; i < 16; ++i) {                                       \
                const float4 e4 = er[i];                                         \
                dot = fmaf(xF[(4 * i + 0) * 132 + c], e4.x, dot);                \
                dot = fmaf(xF[(4 * i + 1) * 132 + c], e4.y, dot);                \
                dot = fmaf(xF[(4 * i + 2) * 132 + c], e4.z, dot);                \
                dot = fmaf(xF[(4 * i + 3) * 132 + c], e4.w, dot);                \
            }                                                                    \
            const float Sec = ws[WS_SE + cd];                                    \
            float dk;                                                            \
            {                                                                    \
                _Pragma("clang fp contract(off)")                                \
                const float tt2 = Sx + Sec;                                      \
                dk = tt2 - 2.0f * dot;                                           \
            }                                                                    \
            if (dk < bd || (dk == bd && cd < bi)) { bd = dk; bi = cd; }          \
        }                                                                        \
        bk[t] = bi;                                                              \
        out[OUT_IDX + n0 + t] = (float)bi;                                       \
        float* qp = out + OUT_Q + (size_t)b * (DIM * HWSZ) + hw0 + t;            \
        const float4* eb4 = (const float4*)(emb + bi * DIM);                     \
        _Pragma("unroll")                                                        \
        for (int i = 0; i < 16; ++i) {                                           \
            const float4 e4 = eb4[i];                                            \
            const float ev[4] = {e4.x, e4.y, e4.z, e4.w};                        \
            _Pragma("unroll")                                                    \
            for (int q = 0; q < 4; ++q) {                                        \
                const int d = 4 * i + q;                                         \
                qp[(size_t)d * HWSZ] = ev[q];                                    \
                const float df = ev[q] - xF[d * 132 + c];                        \
                lsum = fmaf(df, df, lsum);                                       \
            }                                                                    \
        }                                                                        \
        atomicAdd(ws + WS_CNT + bi, 1.0f);                                       \
    }

#define ESUM(hh)                                                                 \
    {                                                                            \
        float* es = ws + WS_ESUM;                                                \
        _Pragma("unroll 1")                                                      \
        for (int j = 0; j < 32; ++j) {                                           \
            const int p  = (w << 5) + j;                                         \
            const int pid = bk[(hh) * 128 + p];                                  \
            atomicAdd(es + (pid << 6) + lane, xF[lane * 132 + p]);               \
        }                                                                        \
    }

    STAGE(0);
    __syncthreads();
    RECHECK_EPI(0);
    __syncthreads();
    ESUM(0);
    __syncthreads();
    STAGE(1);
    __syncthreads();
    RECHECK_EPI(1);
    __syncthreads();
    ESUM(1);

    // loss reduce (each thread contributed from exactly one half)
#pragma unroll
    for (int off = 32; off > 0; off >>= 1) lsum += __shfl_down(lsum, off, 64);
    if (lane == 0) wred[w] = lsum;
    __syncthreads();
    if (t == 0) atomicAdd(ws + WS_LOSS, (wred[0] + wred[1]) + (wred[2] + wred[3]));
}

__global__ __launch_bounds__(256) void vq_cs(const float* __restrict__ ema_cs,
                                             float* __restrict__ out,
                                             float* __restrict__ ws) {
    const int k = blockIdx.x * 256 + threadIdx.x;   // grid 4 -> k < 1024
    const float ncs = fmaf(0.01f, ws[WS_CNT + k], 0.99f * ema_cs[k]);
    out[OUT_CS + k] = ncs;
    float s = ncs;
#pragma unroll
    for (int off = 32; off > 0; off >>= 1) s += __shfl_down(s, off, 64);
    if ((threadIdx.x & 63) == 0) atomicAdd(ws + WS_NSUM, s);
}

__global__ __launch_bounds__(256) void vq_final_b(const float* __restrict__ ema_w,
                                                  float* __restrict__ out,
                                                  float* __restrict__ ws) {
    const int i = blockIdx.x * 256 + threadIdx.x;   // 65536
    const int k = i >> 6;
    const float nsum = ws[WS_NSUM];
    const float ncs  = out[OUT_CS + k];
    const float csz  = (ncs + 1e-5f) / (nsum + 1024.0f * 1e-5f) * nsum;
    const float nw   = fmaf(0.01f, ws[WS_ESUM + i], 0.99f * ema_w[i]);
    out[OUT_EMAW + i] = nw;
    out[OUT_EMB  + i] = nw / csz;
    if (i == 0) out[OUT_LOSS] = 1.25f * ws[WS_LOSS] * (1.0f / 8388608.0f);
}

extern "C" void kernel_launch(void* const* d_in, const int* in_sizes, int n_in,
                              void* d_out, int out_size, void* d_ws, size_t ws_size,
                              hipStream_t stream) {
    const float* in   = (const float*)d_in[0];
    const float* emb  = (const float*)d_in[1];
    const float* ecs  = (const float*)d_in[2];
    const float* emaw = (const float*)d_in[3];
    float* out = (float*)d_out;
    float* ws  = (float*)d_ws;

    vq_init<<<261, 256, 0, stream>>>(emb, ws);
    vq_main<<<NPIX / 256, 256, 0, stream>>>(in, emb, out, ws);
    vq_cs<<<4, 256, 0, stream>>>(ecs, out, ws);
    vq_final_b<<<256, 256, 0, stream>>>(emaw, out, ws);
}

// Round 7
// 216.050 us; speedup vs baseline: 5.3168x; 1.1201x over previous
//
#include <hip/hip_runtime.h>

#define NUM_K 1024
#define DIM 64
#define HWSZ 4096            // 64*64
#define NPIX 131072          // 32*64*64

// output element offsets (float32 elements)
#define OUT_Q    0u
#define OUT_LOSS 8388608u
#define OUT_IDX  8388609u
#define OUT_CS   8519681u
#define OUT_EMAW 8520705u
#define OUT_EMB  8586241u

// workspace layout (float32 elements)
#define WS_SE    0          // 1024
#define WS_CNT   1024       // 1024
#define WS_ESUM  2048       // 65536
#define WS_LOSS  67584
#define WS_NSUM  67585
#define WS_EBF   67840      // 32768 u32 (8192 uint4: E bf16 fragments)
#define WS_ZERO_BEG 1024
#define WS_ZERO_LEN 66562   // cnt + esum + loss + nsum

#define PIXB   128
#define MARGIN 1.6e-3f      // >= rigorous bf16 error bound (1.5e-3)

using bf16x8 = __attribute__((ext_vector_type(8))) short;
using f32x4  = __attribute__((ext_vector_type(4))) float;

// f32 -> bf16 round-to-nearest-even (internal approximation only)
__device__ __forceinline__ unsigned short f2bf(float f) {
    unsigned u = __float_as_uint(f);
    u += 0x7FFFu + ((u >> 16) & 1u);
    return (unsigned short)(u >> 16);
}

// numpy pairwise_sum emulation for sum(a[i]^2), n=64 fp32, contiguous (bit-exact r2-r6)
__device__ __forceinline__ float np_sumsq64(const float* __restrict__ a) {
#pragma clang fp contract(off)
    float r0 = a[0] * a[0], r1 = a[1] * a[1], r2 = a[2] * a[2], r3 = a[3] * a[3];
    float r4 = a[4] * a[4], r5 = a[5] * a[5], r6 = a[6] * a[6], r7 = a[7] * a[7];
    for (int i = 8; i < 64; i += 8) {
        r0 += a[i + 0] * a[i + 0];
        r1 += a[i + 1] * a[i + 1];
        r2 += a[i + 2] * a[i + 2];
        r3 += a[i + 3] * a[i + 3];
        r4 += a[i + 4] * a[i + 4];
        r5 += a[i + 5] * a[i + 5];
        r6 += a[i + 6] * a[i + 6];
        r7 += a[i + 7] * a[i + 7];
    }
    return ((r0 + r1) + (r2 + r3)) + ((r4 + r5) + (r6 + r7));
}

// same, strided source (xF column)
__device__ __forceinline__ float np_sumsq64_s(const float* __restrict__ a, int stride) {
#pragma clang fp contract(off)
    float r[8];
#pragma unroll
    for (int j = 0; j < 8; ++j) { const float v = a[j * stride]; r[j] = v * v; }
#pragma unroll
    for (int i = 8; i < 64; i += 8)
#pragma unroll
        for (int j = 0; j < 8; ++j) { const float v = a[(i + j) * stride]; r[j] += v * v; }
    return ((r[0] + r[1]) + (r[2] + r[3])) + ((r[4] + r[5]) + (r[6] + r[7]));
}

__global__ __launch_bounds__(256) void vq_init(const float* __restrict__ emb,
                                               float* __restrict__ ws) {
    const int t = blockIdx.x * 256 + threadIdx.x;
    if (t < WS_ZERO_LEN) ws[WS_ZERO_BEG + t] = 0.0f;
    if (t < NUM_K) ws[WS_SE + t] = np_sumsq64(emb + t * DIM);
    if (t < 8192) {          // EbF[ct][h][lane] : code=ct*16+(lane&15), d=h*32+8*(lane>>4)+e
        const int ct = t >> 7, h = (t >> 6) & 1, ln = t & 63;
        const int code = ct * 16 + (ln & 15), g = ln >> 4;
        const float* er = emb + code * DIM + h * 32 + g * 8;
        unsigned s[8];
#pragma unroll
        for (int e = 0; e < 8; ++e) s[e] = f2bf(er[e]);
        uint4 v = make_uint4(s[0] | (s[1] << 16), s[2] | (s[3] << 16),
                             s[4] | (s[5] << 16), s[6] | (s[7] << 16));
        ((uint4*)(ws + WS_EBF))[t] = v;
    }
}

__global__ __launch_bounds__(256) void vq_main(const float* __restrict__ in,
                                               const float* __restrict__ emb,
                                               float* __restrict__ out,
                                               float* __restrict__ ws) {
    __shared__ __align__(16) float xF[DIM * 132];   // 33792 B: [d][128 px], pad->132
    __shared__ __align__(16) float SeL[NUM_K];      // 4096 B
    __shared__ float          redM[4][PIXB];        // per-wave per-pixel min
    __shared__ int            cnt_l[PIXB];
    __shared__ unsigned short cand[PIXB * 12];
    __shared__ int            bk[PIXB];
    __shared__ float          wred[4];

    const int t    = threadIdx.x;
    const int lane = t & 63, w = t >> 6;
    const int g    = lane >> 4, cpix = lane & 15;
    const int bid  = blockIdx.x;
    const int b    = bid >> 5;                 // 32 blocks per image
    const int hw0  = (bid & 31) << 7;          // 128 pixels per block
    const int n0   = bid << 7;

    const float* inb = in + (size_t)b * (DIM * HWSZ);

    // ---- stage x (128 px, 64 d) + Se ----
    {
        const float4* s4 = (const float4*)(inb + hw0);
#pragma unroll
        for (int i = 0; i < 8; ++i) {
            const int fi = t + i * 256;              // 2048 float4s
            const int d = fi >> 5, p4 = fi & 31;
            *(float4*)&xF[d * 132 + p4 * 4] = s4[(size_t)d * 1024 + p4];
        }
        ((float4*)SeL)[t] = ((const float4*)(ws + WS_SE))[t];
        if (t < PIXB) cnt_l[t] = 0;
    }
    __syncthreads();

    // ---- B-frags for all 8 pixel-tiles (every wave needs all pixels) ----
    bf16x8 Bfr[8][2];
#pragma unroll
    for (int tt = 0; tt < 8; ++tt) {
        const int p = tt * 16 + cpix;
#pragma unroll
        for (int h = 0; h < 2; ++h) {
            bf16x8 v;
#pragma unroll
            for (int e = 0; e < 8; ++e)
                v[e] = (short)f2bf(xF[(h * 32 + g * 8 + e) * 132 + p]);
            Bfr[tt][h] = v;
        }
    }
    // Sx per pixel (threads 0..127), numpy pairwise order (bit-exact)
    float Sx = 0.0f;
    if (t < PIXB) Sx = np_sumsq64_s(xF + t, 132);

    const bf16x8* Ef  = (const bf16x8*)(ws + WS_EBF);
    const int     ct0 = w << 4;                  // this wave's 16-ct quarter

    // ---- pass 1: MFMA scan of own K-quarter, per-pixel min ----
    float mn[8];
#pragma unroll
    for (int tt = 0; tt < 8; ++tt) mn[tt] = 3.4e38f;

#pragma unroll 4
    for (int ci = 0; ci < 16; ++ci) {
        const int ct = ct0 + ci;
        const bf16x8 A0 = Ef[(ct * 2 + 0) * 64 + lane];
        const bf16x8 A1 = Ef[(ct * 2 + 1) * 64 + lane];
        const f32x4  se = *(const f32x4*)&SeL[(ct << 4) + (g << 2)];
#pragma unroll
        for (int tt = 0; tt < 8; ++tt) {
            f32x4 acc = {0.f, 0.f, 0.f, 0.f};
            acc = __builtin_amdgcn_mfma_f32_16x16x32_bf16(A0, Bfr[tt][0], acc, 0, 0, 0);
            acc = __builtin_amdgcn_mfma_f32_16x16x32_bf16(A1, Bfr[tt][1], acc, 0, 0, 0);
            const float s0 = fmaf(-2.0f, acc[0], se[0]);
            const float s1 = fmaf(-2.0f, acc[1], se[1]);
            const float s2 = fmaf(-2.0f, acc[2], se[2]);
            const float s3 = fmaf(-2.0f, acc[3], se[3]);
            mn[tt] = fminf(mn[tt], fminf(fminf(s0, s1), fminf(s2, s3)));
        }
    }

    // ---- cross-wave per-pixel min -> threshold ----
#pragma unroll
    for (int tt = 0; tt < 8; ++tt) {
        float m2 = mn[tt];
        m2 = fminf(m2, __shfl_xor(m2, 16, 64));
        m2 = fminf(m2, __shfl_xor(m2, 32, 64));
        if (g == 0) redM[w][tt * 16 + cpix] = m2;
    }
    __syncthreads();
    float thr[8];
#pragma unroll
    for (int tt = 0; tt < 8; ++tt) {
        const int p = tt * 16 + cpix;
        thr[tt] = fminf(fminf(redM[0][p], redM[1][p]),
                        fminf(redM[2][p], redM[3][p])) + MARGIN;
    }

    // ---- pass 2: bit-identical recompute, collect candidates <= thr ----
#pragma unroll 4
    for (int ci = 0; ci < 16; ++ci) {
        const int ct = ct0 + ci;
        const bf16x8 A0 = Ef[(ct * 2 + 0) * 64 + lane];
        const bf16x8 A1 = Ef[(ct * 2 + 1) * 64 + lane];
        const f32x4  se = *(const f32x4*)&SeL[(ct << 4) + (g << 2)];
#pragma unroll
        for (int tt = 0; tt < 8; ++tt) {
            f32x4 acc = {0.f, 0.f, 0.f, 0.f};
            acc = __builtin_amdgcn_mfma_f32_16x16x32_bf16(A0, Bfr[tt][0], acc, 0, 0, 0);
            acc = __builtin_amdgcn_mfma_f32_16x16x32_bf16(A1, Bfr[tt][1], acc, 0, 0, 0);
#pragma unroll
            for (int r = 0; r < 4; ++r) {
                const float s = fmaf(-2.0f, acc[r], se[r]);
                if (s <= thr[tt]) {
                    const int p    = tt * 16 + cpix;
                    const int code = (ct << 4) + (g << 2) + r;
                    const int sl   = atomicAdd(&cnt_l[p], 1);
                    if (sl < 12) cand[p * 12 + sl] = (unsigned short)code;
                }
            }
        }
    }
    __syncthreads();

    // ---- exact recheck (threads 0..127, one pixel each) ----
    if (t < PIXB) {
        const int c  = t;
        const int cc = min(cnt_l[c], 12);
        float bd = 3.4e38f; int bi = NUM_K;
        for (int j = 0; j < cc; ++j) {
            const int cd = cand[c * 12 + j];
            const float4* er = (const float4*)(emb + cd * DIM);
            float dot = 0.0f;
#pragma unroll
            for (int i = 0; i < 16; ++i) {
                const float4 e4 = er[i];
                dot = fmaf(xF[(4 * i + 0) * 132 + c], e4.x, dot);
                dot = fmaf(xF[(4 * i + 1) * 132 + c], e4.y, dot);
                dot = fmaf(xF[(4 * i + 2) * 132 + c], e4.z, dot);
                dot = fmaf(xF[(4 * i + 3) * 132 + c], e4.w, dot);
            }
            const float Sec = SeL[cd];
            float dk;
            {
#pragma clang fp contract(off)
                const float tt2 = Sx + Sec;
                dk = tt2 - 2.0f * dot;
            }
            if (dk < bd || (dk == bd && cd < bi)) { bd = dk; bi = cd; }
        }
        bk[c] = bi;
        out[OUT_IDX + n0 + c] = (float)bi;
        atomicAdd(ws + WS_CNT + bi, 1.0f);
    }
    __syncthreads();

    // ---- quantized write + loss (all 256: 32 d's of one pixel each) ----
    float lsum = 0.0f;
    {
        const int px = t & 127, dh = t >> 7;
        const int id = bk[px];
        float* qp = out + OUT_Q + (size_t)b * (DIM * HWSZ) + hw0 + px;
        const float4* eb4 = (const float4*)(emb + (id << 6) + (dh << 5));
#pragma unroll
        for (int i = 0; i < 8; ++i) {
            const float4 e4 = eb4[i];
            const float ev[4] = {e4.x, e4.y, e4.z, e4.w};
#pragma unroll
            for (int q = 0; q < 4; ++q) {
                const int d = (dh << 5) + i * 4 + q;
                qp[(size_t)d * HWSZ] = ev[q];
                const float df = ev[q] - xF[d * 132 + px];
                lsum = fmaf(df, df, lsum);
            }
        }
    }
#pragma unroll
    for (int off = 32; off > 0; off >>= 1) lsum += __shfl_down(lsum, off, 64);
    if (lane == 0) wred[w] = lsum;
    __syncthreads();
    if (t == 0) atomicAdd(ws + WS_LOSS, (wred[0] + wred[1]) + (wred[2] + wred[3]));

    // ---- esum: one coalesced 256B atomic burst per pixel (32 px per wave) ----
    {
        float* es = ws + WS_ESUM;
#pragma unroll 1
        for (int j = 0; j < 32; ++j) {
            const int p   = (w << 5) + j;
            const int pid = bk[p];
            atomicAdd(es + (pid << 6) + lane, xF[lane * 132 + p]);
        }
    }
}

__global__ __launch_bounds__(256) void vq_cs(const float* __restrict__ ema_cs,
                                             float* __restrict__ out,
                                             float* __restrict__ ws) {
    const int k = blockIdx.x * 256 + threadIdx.x;   // grid 4 -> k < 1024
    const float ncs = fmaf(0.01f, ws[WS_CNT + k], 0.99f * ema_cs[k]);
    out[OUT_CS + k] = ncs;
    float s = ncs;
#pragma unroll
    for (int off = 32; off > 0; off >>= 1) s += __shfl_down(s, off, 64);
    if ((threadIdx.x & 63) == 0) atomicAdd(ws + WS_NSUM, s);
}

__global__ __launch_bounds__(256) void vq_final_b(const float* __restrict__ ema_w,
                                                  float* __restrict__ out,
                                                  float* __restrict__ ws) {
    const int i = blockIdx.x * 256 + threadIdx.x;   // 65536
    const int k = i >> 6;
    const float nsum = ws[WS_NSUM];
    const float ncs  = out[OUT_CS + k];
    const float csz  = (ncs + 1e-5f) / (nsum + 1024.0f * 1e-5f) * nsum;
    const float nw   = fmaf(0.01f, ws[WS_ESUM + i], 0.99f * ema_w[i]);
    out[OUT_EMAW + i] = nw;
    out[OUT_EMB  + i] = nw / csz;
    if (i == 0) out[OUT_LOSS] = 1.25f * ws[WS_LOSS] * (1.0f / 8388608.0f);
}

extern "C" void kernel_launch(void* const* d_in, const int* in_sizes, int n_in,
                              void* d_out, int out_size, void* d_ws, size_t ws_size,
                              hipStream_t stream) {
    const float* in   = (const float*)d_in[0];
    const float* emb  = (const float*)d_in[1];
    const float* ecs  = (const float*)d_in[2];
    const float* emaw = (const float*)d_in[3];
    float* out = (float*)d_out;
    float* ws  = (float*)d_ws;

    vq_init<<<261, 256, 0, stream>>>(emb, ws);
    vq_main<<<NPIX / PIXB, 256, 0, stream>>>(in, emb, out, ws);
    vq_cs<<<4, 256, 0, stream>>>(ecs, out, ws);
    vq_final_b<<<256, 256, 0, stream>>>(emaw, out, ws);
}

// Round 9
// 201.855 us; speedup vs baseline: 5.6907x; 1.0703x over previous
//
#include <hip/hip_runtime.h>

#define NUM_K 1024
#define DIM 64
#define HWSZ 4096            // 64*64
#define NPIX 131072          // 32*64*64

// output element offsets (float32 elements)
#define OUT_Q    0u
#define OUT_LOSS 8388608u
#define OUT_IDX  8388609u
#define OUT_CS   8519681u
#define OUT_EMAW 8520705u
#define OUT_EMB  8586241u

// workspace layout (float32 elements)
#define WS_SE    0          // 1024
#define WS_CNT   1024       // 1024
#define WS_ESUM  2048       // 65536
#define WS_LOSS  67584
#define WS_EBF   67840      // 32768 u32 (8192 uint4: E bf16 fragments)
#define WS_ZERO_BEG 1024
#define WS_ZERO_LEN 66561   // cnt + esum + loss

#define PIXB   64
#define XSTR   65           // xF row stride: bank=(d+p)%32 -> <=2-way everywhere
#define MARGIN 1.6e-3f      // >= rigorous bf16 error bound (1.5e-3)

using bf16x8 = __attribute__((ext_vector_type(8))) short;
using f32x4  = __attribute__((ext_vector_type(4))) float;

// f32 -> bf16 round-to-nearest-even (internal approximation only)
__device__ __forceinline__ unsigned short f2bf(float f) {
    unsigned u = __float_as_uint(f);
    u += 0x7FFFu + ((u >> 16) & 1u);
    return (unsigned short)(u >> 16);
}

// numpy pairwise_sum emulation for sum(a[i]^2), n=64 fp32, contiguous (bit-exact r2-r7)
__device__ __forceinline__ float np_sumsq64(const float* __restrict__ a) {
#pragma clang fp contract(off)
    float r0 = a[0] * a[0], r1 = a[1] * a[1], r2 = a[2] * a[2], r3 = a[3] * a[3];
    float r4 = a[4] * a[4], r5 = a[5] * a[5], r6 = a[6] * a[6], r7 = a[7] * a[7];
    for (int i = 8; i < 64; i += 8) {
        r0 += a[i + 0] * a[i + 0];
        r1 += a[i + 1] * a[i + 1];
        r2 += a[i + 2] * a[i + 2];
        r3 += a[i + 3] * a[i + 3];
        r4 += a[i + 4] * a[i + 4];
        r5 += a[i + 5] * a[i + 5];
        r6 += a[i + 6] * a[i + 6];
        r7 += a[i + 7] * a[i + 7];
    }
    return ((r0 + r1) + (r2 + r3)) + ((r4 + r5) + (r6 + r7));
}

// same, strided source (xF column)
__device__ __forceinline__ float np_sumsq64_s(const float* __restrict__ a, int stride) {
#pragma clang fp contract(off)
    float r[8];
#pragma unroll
    for (int j = 0; j < 8; ++j) { const float v = a[j * stride]; r[j] = v * v; }
#pragma unroll
    for (int i = 8; i < 64; i += 8)
#pragma unroll
        for (int j = 0; j < 8; ++j) { const float v = a[(i + j) * stride]; r[j] += v * v; }
    return ((r[0] + r[1]) + (r[2] + r[3])) + ((r[4] + r[5]) + (r[6] + r[7]));
}

__global__ __launch_bounds__(256) void vq_init(const float* __restrict__ emb,
                                               float* __restrict__ ws) {
    const int t = blockIdx.x * 256 + threadIdx.x;
    if (t < WS_ZERO_LEN) ws[WS_ZERO_BEG + t] = 0.0f;
    if (t < NUM_K) ws[WS_SE + t] = np_sumsq64(emb + t * DIM);
    if (t < 8192) {          // EbF[ct][h][lane] : code=ct*16+(lane&15), d=h*32+8*(lane>>4)+e
        const int ct = t >> 7, h = (t >> 6) & 1, ln = t & 63;
        const int code = ct * 16 + (ln & 15), g = ln >> 4;
        const float* er = emb + code * DIM + h * 32 + g * 8;
        unsigned s[8];
#pragma unroll
        for (int e = 0; e < 8; ++e) s[e] = f2bf(er[e]);
        uint4 v = make_uint4(s[0] | (s[1] << 16), s[2] | (s[3] << 16),
                             s[4] | (s[5] << 16), s[6] | (s[7] << 16));
        ((uint4*)(ws + WS_EBF))[t] = v;
    }
}

__global__ __launch_bounds__(256, 5) void vq_main(const float* __restrict__ in,
                                                  const float* __restrict__ emb,
                                                  float* __restrict__ out,
                                                  float* __restrict__ ws) {
    __shared__ float xF[DIM * XSTR];            // 16640 B: [d][64 px], stride 65
    __shared__ float SeL[NUM_K];                // 4096 B
    __shared__ float redM[4][PIXB];             // 1024 B
    __shared__ int            cnt_l[PIXB];
    __shared__ unsigned short cand[PIXB * 12];
    __shared__ int            bk[PIXB];
    __shared__ float          wred[4];

    const int t    = threadIdx.x;
    const int lane = t & 63, w = t >> 6;
    const int g    = lane >> 4, cpix = lane & 15;
    const int bid  = blockIdx.x;
    const int b    = bid >> 6;                 // 64 blocks per image
    const int hw0  = (bid & 63) << 6;          // 64 pixels per block
    const int n0   = bid << 6;

    const float* inb = in + (size_t)b * (DIM * HWSZ);

    // ---- stage x (64 px x 64 d) + Se ----
    {
        const float4* s4 = (const float4*)(inb + hw0);
#pragma unroll
        for (int i = 0; i < 4; ++i) {
            const int fi = t + i * 256;              // 1024 float4s
            const int d = fi >> 4, p4 = fi & 15;
            const float4 v = s4[(size_t)d * 1024 + p4];
            float* dst = &xF[d * XSTR + p4 * 4];     // stride-65: conflict-free scalar writes
            dst[0] = v.x; dst[1] = v.y; dst[2] = v.z; dst[3] = v.w;
        }
        ((float4*)SeL)[t] = ((const float4*)(ws + WS_SE))[t];
        if (t < PIXB) cnt_l[t] = 0;
    }
    __syncthreads();

    // ---- B-frags for the block's 4 pixel-tiles (every wave needs all pixels) ----
    bf16x8 Bfr[4][2];
#pragma unroll
    for (int tt = 0; tt < 4; ++tt) {
        const int p = tt * 16 + cpix;
#pragma unroll
        for (int h = 0; h < 2; ++h) {
            bf16x8 v;
#pragma unroll
            for (int e = 0; e < 8; ++e)
                v[e] = (short)f2bf(xF[(h * 32 + g * 8 + e) * XSTR + p]);
            Bfr[tt][h] = v;
        }
    }
    // Sx per pixel (threads 0..63), numpy pairwise order (bit-exact)
    float Sx = 0.0f;
    if (t < PIXB) Sx = np_sumsq64_s(xF + t, XSTR);

    const bf16x8* Ef  = (const bf16x8*)(ws + WS_EBF);
    const int     ct0 = w << 4;                  // this wave's 16-ct quarter

    // ---- pass 1: MFMA scan of own K-quarter, per-pixel min ----
    float mn[4];
#pragma unroll
    for (int tt = 0; tt < 4; ++tt) mn[tt] = 3.4e38f;

#pragma unroll 4
    for (int ci = 0; ci < 16; ++ci) {
        const int ct = ct0 + ci;
        const bf16x8 A0 = Ef[(ct * 2 + 0) * 64 + lane];
        const bf16x8 A1 = Ef[(ct * 2 + 1) * 64 + lane];
        const f32x4  se = *(const f32x4*)&SeL[(ct << 4) + (g << 2)];
#pragma unroll
        for (int tt = 0; tt < 4; ++tt) {
            f32x4 acc = {0.f, 0.f, 0.f, 0.f};
            acc = __builtin_amdgcn_mfma_f32_16x16x32_bf16(A0, Bfr[tt][0], acc, 0, 0, 0);
            acc = __builtin_amdgcn_mfma_f32_16x16x32_bf16(A1, Bfr[tt][1], acc, 0, 0, 0);
            const float s0 = fmaf(-2.0f, acc[0], se[0]);
            const float s1 = fmaf(-2.0f, acc[1], se[1]);
            const float s2 = fmaf(-2.0f, acc[2], se[2]);
            const float s3 = fmaf(-2.0f, acc[3], se[3]);
            mn[tt] = fminf(fminf(fminf(s0, s1), fminf(s2, s3)), mn[tt]);  // min3-fusable
        }
    }

    // ---- cross-wave per-pixel min -> threshold ----
#pragma unroll
    for (int tt = 0; tt < 4; ++tt) {
        float m2 = mn[tt];
        m2 = fminf(m2, __shfl_xor(m2, 16, 64));
        m2 = fminf(m2, __shfl_xor(m2, 32, 64));
        if (g == 0) redM[w][tt * 16 + cpix] = m2;
    }
    __syncthreads();
    float thr[4];
#pragma unroll
    for (int tt = 0; tt < 4; ++tt) {
        const int p = tt * 16 + cpix;
        thr[tt] = fminf(fminf(redM[0][p], redM[1][p]),
                        fminf(redM[2][p], redM[3][p])) + MARGIN;
    }

    // ---- pass 2: bit-identical recompute, collect candidates <= thr ----
#pragma unroll 4
    for (int ci = 0; ci < 16; ++ci) {
        const int ct = ct0 + ci;
        const bf16x8 A0 = Ef[(ct * 2 + 0) * 64 + lane];
        const bf16x8 A1 = Ef[(ct * 2 + 1) * 64 + lane];
#pragma unroll
        for (int tt = 0; tt < 4; ++tt) {
            f32x4 acc = {0.f, 0.f, 0.f, 0.f};
            acc = __builtin_amdgcn_mfma_f32_16x16x32_bf16(A0, Bfr[tt][0], acc, 0, 0, 0);
            acc = __builtin_amdgcn_mfma_f32_16x16x32_bf16(A1, Bfr[tt][1], acc, 0, 0, 0);
            const f32x4 se = *(const f32x4*)&SeL[(ct << 4) + (g << 2)];
#pragma unroll
            for (int r = 0; r < 4; ++r) {
                const float s = fmaf(-2.0f, acc[r], se[r]);
                if (s <= thr[tt]) {
                    const int p    = tt * 16 + cpix;
                    const int code = (ct << 4) + (g << 2) + r;
                    const int sl   = atomicAdd(&cnt_l[p], 1);
                    if (sl < 12) cand[p * 12 + sl] = (unsigned short)code;
                }
            }
        }
    }
    __syncthreads();

    // ---- exact recheck (threads 0..63, one pixel each) ----
    if (t < PIXB) {
        const int c  = t;
        const int cc = min(cnt_l[c], 12);
        float bd = 3.4e38f; int bi = NUM_K;
        for (int j = 0; j < cc; ++j) {
            const int cd = cand[c * 12 + j];
            const float4* er = (const float4*)(emb + cd * DIM);
            float dot = 0.0f;
#pragma unroll
            for (int i = 0; i < 16; ++i) {
                const float4 e4 = er[i];
                dot = fmaf(xF[(4 * i + 0) * XSTR + c], e4.x, dot);
                dot = fmaf(xF[(4 * i + 1) * XSTR + c], e4.y, dot);
                dot = fmaf(xF[(4 * i + 2) * XSTR + c], e4.z, dot);
                dot = fmaf(xF[(4 * i + 3) * XSTR + c], e4.w, dot);
            }
            const float Sec = SeL[cd];
            float dk;
            {
#pragma clang fp contract(off)
                const float tt2 = Sx + Sec;
                dk = tt2 - 2.0f * dot;
            }
            if (dk < bd || (dk == bd && cd < bi)) { bd = dk; bi = cd; }
        }
        bk[c] = bi;
        out[OUT_IDX + n0 + c] = (float)bi;
        atomicAdd(ws + WS_CNT + bi, 1.0f);
    }
    __syncthreads();

    // ---- quantized write + loss (256 thr: 16 d's of one pixel each) ----
    float lsum = 0.0f;
    {
        const int px = t & 63, dq = t >> 6;
        const int id = bk[px];
        float* qp = out + OUT_Q + (size_t)b * (DIM * HWSZ) + hw0 + px;
        const float4* eb4 = (const float4*)(emb + (id << 6) + (dq << 4));
#pragma unroll
        for (int i = 0; i < 4; ++i) {
            const float4 e4 = eb4[i];
            const float ev[4] = {e4.x, e4.y, e4.z, e4.w};
#pragma unroll
            for (int q = 0; q < 4; ++q) {
                const int d = (dq << 4) + i * 4 + q;
                qp[(size_t)d * HWSZ] = ev[q];
                const float df = ev[q] - xF[d * XSTR + px];
                lsum = fmaf(df, df, lsum);
            }
        }
    }
#pragma unroll
    for (int off = 32; off > 0; off >>= 1) lsum += __shfl_down(lsum, off, 64);
    if (lane == 0) wred[w] = lsum;
    __syncthreads();
    if (t == 0) atomicAdd(ws + WS_LOSS, (wred[0] + wred[1]) + (wred[2] + wred[3]));

    // ---- esum: one coalesced 256B atomic burst per pixel (16 px per wave) ----
    {
        float* es = ws + WS_ESUM;
#pragma unroll 1
        for (int j = 0; j < 16; ++j) {
            const int p   = (w << 4) + j;
            const int pid = bk[p];
            atomicAdd(es + (pid << 6) + lane, xF[lane * XSTR + p]);
        }
    }
}

// merged: per-block redundant nsum (L2-resident 8KB) + EMA finalize
__global__ __launch_bounds__(256) void vq_final(const float* __restrict__ ema_cs,
                                                const float* __restrict__ ema_w,
                                                float* __restrict__ out,
                                                float* __restrict__ ws) {
    __shared__ float nred[4];
    const int t = threadIdx.x, lane = t & 63, w = t >> 6;

    float s = 0.0f;
#pragma unroll
    for (int j = 0; j < 4; ++j) {
        const int k = t + j * 256;
        s += fmaf(0.01f, ws[WS_CNT + k], 0.99f * ema_cs[k]);
    }
#pragma unroll
    for (int off = 32; off > 0; off >>= 1) s += __shfl_down(s, off, 64);
    if (lane == 0) nred[w] = s;
    __syncthreads();
    const float nsum = (nred[0] + nred[1]) + (nred[2] + nred[3]);

    if (blockIdx.x == 0) {
#pragma unroll
        for (int j = 0; j < 4; ++j) {
            const int k = t + j * 256;
            out[OUT_CS + k] = fmaf(0.01f, ws[WS_CNT + k], 0.99f * ema_cs[k]);
        }
    }

    const int i = blockIdx.x * 256 + t;   // 65536
    const int k = i >> 6;
    const float ncs = fmaf(0.01f, ws[WS_CNT + k], 0.99f * ema_cs[k]);
    const float csz = (ncs + 1e-5f) / (nsum + 1024.0f * 1e-5f) * nsum;
    const float nw  = fmaf(0.01f, ws[WS_ESUM + i], 0.99f * ema_w[i]);
    out[OUT_EMAW + i] = nw;
    out[OUT_EMB  + i] = nw / csz;
    if (i == 0) out[OUT_LOSS] = 1.25f * ws[WS_LOSS] * (1.0f / 8388608.0f);
}

extern "C" void kernel_launch(void* const* d_in, const int* in_sizes, int n_in,
                              void* d_out, int out_size, void* d_ws, size_t ws_size,
                              hipStream_t stream) {
    const float* in   = (const float*)d_in[0];
    const float* emb  = (const float*)d_in[1];
    const float* ecs  = (const float*)d_in[2];
    const float* emaw = (const float*)d_in[3];
    float* out = (float*)d_out;
    float* ws  = (float*)d_ws;

    vq_init<<<261, 256, 0, stream>>>(emb, ws);
    vq_main<<<NPIX / PIXB, 256, 0, stream>>>(in, emb, out, ws);
    vq_final<<<256, 256, 0, stream>>>(ecs, emaw, out, ws);
}